// Round 8
// baseline (111.920 us; speedup 1.0000x reference)
//
#include <hip/hip_runtime.h>

// ChannelKiller: out[b,c,s] = (c==0) ? x[b,c,s] : 0
// x: [16, 8, 1048576] fp32. Channel row = 2^18 float4, batch = 2^21 float4.
// R8: single dispatch, loop-FREE (the R7 lever: no loop-carried branch),
// but 4 float4 ops per thread -> 4x fewer blocks (32768), 1 KB contiguous
// per wave-op, 4-deep store ILP per lane. Zero double-writes.
//   blocks [0, 28672):  zero channels 1..7  (1024 float4 per block)
//   blocks [28672, 32768): copy channel 0   (1024 float4 per block)

typedef float f32x4 __attribute__((ext_vector_type(4)));

#define S_LOG2 18
#define ZBLK_PER_BATCH 1792          // 7*2^18/1024 zero blocks per batch
#define NZB (16 * ZBLK_PER_BATCH)    // 28672
#define CBLK_PER_BATCH 256           // 2^18/1024 copy blocks per batch
#define NCB (16 * CBLK_PER_BATCH)    // 4096

__global__ __launch_bounds__(256)
void ChannelKiller_54365696033605_kernel(const f32x4* __restrict__ x,
                                         f32x4* __restrict__ out) {
    const int bid = blockIdx.x;
    const int tid = threadIdx.x;

    if (bid < NZB) {
        int batch = bid / ZBLK_PER_BATCH;          // scalar, compile-time magic div
        int rem = bid - batch * ZBLK_PER_BATCH;
        // base of this block's 1024-float4 chunk inside channels 1..7
        int base = (batch << (S_LOG2 + 3)) + (1 << S_LOG2) + (rem << 10) + tid;
        const f32x4 zf = {0.f, 0.f, 0.f, 0.f};
        out[base]       = zf;
        out[base + 256] = zf;
        out[base + 512] = zf;
        out[base + 768] = zf;
    } else {
        int cid = bid - NZB;
        int batch = cid >> 8;                      // 256 copy blocks per batch
        int rem = cid & (CBLK_PER_BATCH - 1);
        int base = (batch << (S_LOG2 + 3)) + (rem << 10) + tid;   // channel 0
        f32x4 a = x[base];
        f32x4 b = x[base + 256];
        f32x4 c = x[base + 512];
        f32x4 d = x[base + 768];
        out[base]       = a;
        out[base + 256] = b;
        out[base + 512] = c;
        out[base + 768] = d;
    }
}

extern "C" void kernel_launch(void* const* d_in, const int* in_sizes, int n_in,
                              void* d_out, int out_size, void* d_ws, size_t ws_size,
                              hipStream_t stream) {
    const f32x4* x = (const f32x4*)d_in[0];
    f32x4* out = (f32x4*)d_out;
    ChannelKiller_54365696033605_kernel<<<NZB + NCB, 256, 0, stream>>>(x, out);
}

// Round 9
// 99.752 us; speedup vs baseline: 1.1220x; 1.1220x over previous
//
#include <hip/hip_runtime.h>

// ChannelKiller: out[b,c,s] = (c==0) ? x[b,c,s] : 0
// x: [16, 8, 1048576] fp32. Channel row = 2^18 float4, batch = 2^21 float4.
// R9 = R7 revert (best measured: 100.1 us, 6.03 TB/s effective on 604 MB).
// Single dispatch, loop-free, exactly one float4 memory op per thread:
//   blocks [0, 114688):     zero channels 1..7 (470 MB pure store)
//   blocks [114688, 131072): copy channel 0    (67 MB load + 67 MB store)
// Evidence: looped writers pin at ~5.0 TB/s (R1-R3 122us); 4-op unroll
// regresses (R8 111.9us); memset+copy 107.7us (R4). One-op-per-thread with
// block-consecutive 4 KB chunks is the fastest structure found.

typedef float f32x4 __attribute__((ext_vector_type(4)));

#define S_LOG2 18            // float4 per channel row
#define ZBLK_PER_BATCH 7168  // 7*2^18/256 zero blocks per batch
#define NZB (16 * ZBLK_PER_BATCH)   // 114688 zero blocks
#define CBLK_PER_BATCH 1024  // 2^18/256 copy blocks per batch
#define NCB (16 * CBLK_PER_BATCH)   // 16384 copy blocks

__global__ __launch_bounds__(256)
void ChannelKiller_54365696033605_kernel(const f32x4* __restrict__ x,
                                         f32x4* __restrict__ out) {
    const int bid = blockIdx.x;
    const int tid = threadIdx.x;

    if (bid < NZB) {
        // zero: batch = bid/7168 (scalar, compile-time magic div).
        int batch = bid / ZBLK_PER_BATCH;
        int rem = bid - batch * ZBLK_PER_BATCH;
        // addr covers channels 1..7: base (1<<18) + rem*256 + tid in [2^18, 2^21)
        int addr = (batch << (S_LOG2 + 3)) + (1 << S_LOG2) + (rem << 8) + tid;
        const f32x4 zf = {0.f, 0.f, 0.f, 0.f};
        out[addr] = zf;
    } else {
        int cid = bid - NZB;
        int batch = cid >> 10;             // 1024 copy blocks per batch
        int rem = cid & (CBLK_PER_BATCH - 1);
        int addr = (batch << (S_LOG2 + 3)) + (rem << 8) + tid;  // channel 0
        out[addr] = x[addr];
    }
}

extern "C" void kernel_launch(void* const* d_in, const int* in_sizes, int n_in,
                              void* d_out, int out_size, void* d_ws, size_t ws_size,
                              hipStream_t stream) {
    const f32x4* x = (const f32x4*)d_in[0];
    f32x4* out = (f32x4*)d_out;
    ChannelKiller_54365696033605_kernel<<<NZB + NCB, 256, 0, stream>>>(x, out);
}